// Round 10
// baseline (370.051 us; speedup 1.0000x reference)
//
#include <hip/hip_runtime.h>

#define TT 365
#define NB 16
#define NTH 1024   // 16 waves, 1 M-tile each -> 4 waves/SIMD
#define XLEN (NB * TT * 3)   // 17520 floats

typedef _Float16 halfx8 __attribute__((ext_vector_type(8)));
typedef float floatx4 __attribute__((ext_vector_type(4)));

#define MMH(A, B, C) __builtin_amdgcn_mfma_f32_16x16x32_f16((A), (B), (C), 0, 0, 0)

// Pre-activations arrive PRE-SCALED by -log2e (sigmoid rows) / -2log2e (g rows).
__device__ __forceinline__ float sigm2(float y) {
  return __builtin_amdgcn_rcpf(1.0f + __builtin_amdgcn_exp2f(y));
}
__device__ __forceinline__ float tanh2(float y) {
  return fmaf(2.0f, __builtin_amdgcn_rcpf(1.0f + __builtin_amdgcn_exp2f(y)), -1.0f);
}
__device__ __forceinline__ float tanhc(float c) {   // unscaled cell value
  float e = __builtin_amdgcn_exp2f(-2.8853900817779268f * c);
  return fmaf(2.0f, __builtin_amdgcn_rcpf(1.0f + e), -1.0f);
}
__device__ __forceinline__ unsigned short h16(float v) {
  _Float16 h = (_Float16)v;
  return __builtin_bit_cast(unsigned short, h);
}

// weights -> plain fp16 (RNE); rel err 2^-12, verified harmless (R9 absmax flat)
#define LOADFRAG(SRC, SCALE, HI)                                               \
  do {                                                                         \
    _Pragma("unroll")                                                          \
    for (int jj = 0; jj < 8; ++jj) {                                           \
      (HI)[jj] = (_Float16)((SCALE) * (SRC)[jj]);                              \
    }                                                                          \
  } while (0)

// One timestep, straight-line. ZRP: hoisted lane-offset read ptr (immediate
// LDS offsets). W1/W2: persistent write ptrs into the other buffer.
// All 6 MFMAs issue first (E as two parallel chains); activations follow.
#define STEP(ZRP, W1, W2)                                                      \
  do {                                                                         \
    const halfx8 bh0 = (ZRP)[0],   bh1 = (ZRP)[64];                            \
    const halfx8 bh2 = (ZRP)[128], bh3 = (ZRP)[192];                           \
    const float xv0 = xp[0], xv1 = xp[1], xv2 = xp[2];                         \
    floatx4 e0 = b1v;                                                          \
    floatx4 e1 = {0.f, 0.f, 0.f, 0.f};                                         \
    floatx4 d;                                                                 \
    d[0] = fmaf(wiX[0], xv0, fmaf(wiY[0], xv1, fmaf(wiZ[0], xv2, b0v[0])));    \
    d[1] = fmaf(wiX[1], xv0, fmaf(wiY[1], xv1, fmaf(wiZ[1], xv2, b0v[1])));    \
    d[2] = fmaf(wiX[2], xv0, fmaf(wiY[2], xv1, fmaf(wiZ[2], xv2, b0v[2])));    \
    d[3] = fmaf(wiX[3], xv0, fmaf(wiY[3], xv1, fmaf(wiZ[3], xv2, b0v[3])));    \
    e0 = MMH(a2h[0], bh0, e0);                                                 \
    e1 = MMH(a2h[2], bh2, e1);                                                 \
    e0 = MMH(a2h[1], bh1, e0);                                                 \
    e1 = MMH(a2h[3], bh3, e1);                                                 \
    d  = MMH(a1h[0], bh0, d);                                                  \
    d  = MMH(a1h[1], bh1, d);                                                  \
    const floatx4 e = e0 + e1;                                                 \
    const float i2 = sigm2(e[0]), f2s = sigm2(e[1]);                           \
    const float g2 = tanh2(e[2]), o2 = sigm2(e[3]);                            \
    c2 = fmaf(f2s, c2, i2 * g2);                                               \
    *(W2) = h16(o2 * tanhc(c2));                                               \
    const float i1 = sigm2(d[0]), f1s = sigm2(d[1]);                           \
    const float g1 = tanh2(d[2]), o1 = sigm2(d[3]);                            \
    c1 = fmaf(f1s, c1, i1 * g1);                                               \
    *(W1) = h16(o1 * tanhc(c1));                                               \
    xp += 3;                                                                   \
    __syncthreads();                                                           \
  } while (0)

__global__ __launch_bounds__(NTH)
__attribute__((amdgpu_waves_per_eu(4, 4)))
void lstm2_mfma8(
    const float* __restrict__ x,
    const float* __restrict__ w_ih0, const float* __restrict__ w_hh0,
    const float* __restrict__ b_ih0, const float* __restrict__ b_hh0,
    const float* __restrict__ w_ih1, const float* __restrict__ w_hh1,
    const float* __restrict__ b_ih1, const float* __restrict__ b_hh1,
    float* __restrict__ out)
{
  __shared__ __align__(16) unsigned short Z[2][2048];  // fp16 h: [buf][kt][lane][8]
  __shared__ __align__(16) float xlds[XLEN];

  const int tid  = threadIdx.x;
  const int lane = tid & 63;
  const int wv   = tid >> 6;      // 0..15: one M-tile per wave
  const int n15  = lane & 15;
  const int quad = lane >> 4;
  const int bbase = blockIdx.x * NB;

  const float SS = -1.4426950408889634f;   // sigmoid rows
  const float SG = -2.8853900817779268f;   // g (tanh) rows
  const float sA = ((n15 & 3) == 2) ? SG : SS;

  halfx8 a1h[2];   // [kt]  L1 (K=64)
  halfx8 a2h[4];   // [kt]  L2 (K=128: [w_ih1|w_hh1])
  floatx4 wiX, wiY, wiZ, b0v, b1v;

  {
    const int mt   = wv;
    const int arow = (n15 & 3) * 64 + mt * 4 + (n15 >> 2);   // row-permuted A
    #pragma unroll
    for (int kt = 0; kt < 2; ++kt) {
      const float* src = w_hh0 + arow * 64 + kt * 32 + quad * 8;
      LOADFRAG(src, sA, a1h[kt]);
    }
    #pragma unroll
    for (int kt = 0; kt < 4; ++kt) {
      const int k0 = kt * 32 + quad * 8;
      const float* src = (k0 < 64) ? (w_ih1 + arow * 64 + k0)
                                   : (w_hh1 + arow * 64 + (k0 - 64));
      LOADFRAG(src, sA, a2h[kt]);
    }
    #pragma unroll
    for (int r = 0; r < 4; ++r) {
      const int crow = r * 64 + mt * 4 + quad;
      const float sC = (r == 2) ? SG : SS;
      wiX[r] = sC * w_ih0[crow * 3 + 0];
      wiY[r] = sC * w_ih0[crow * 3 + 1];
      wiZ[r] = sC * w_ih0[crow * 3 + 2];
      b0v[r] = sC * (b_ih0[crow] + b_hh0[crow]);
      b1v[r] = sC * (b_ih1[crow] + b_hh1[crow]);
    }
  }

  const int j = wv * 4 + quad;    // this thread's hidden unit (0..63)
  const int sidx1 = (j >> 5) * 512 + ((j >> 3) & 3) * 128 + n15 * 8 + (j & 7);
  const int sidx2 = sidx1 + 1024;

  {
    const float* xg = x + (size_t)bbase * (TT * 3);
    for (int i = tid; i < XLEN; i += NTH) xlds[i] = xg[i];
    for (int i = tid; i < 2048; i += NTH) { Z[0][i] = 0; Z[1][i] = 0; }
  }

  float c1 = 0.f, c2 = 0.f;

  // hoisted LDS pointers (reads use immediate offsets off a single base)
  const halfx8* const Z0p = (const halfx8*)&Z[0][0] + lane;
  const halfx8* const Z1p = (const halfx8*)&Z[1][0] + lane;
  unsigned short* const w1_0 = &Z[0][0] + sidx1;   // h1 -> buf0
  unsigned short* const w2_0 = &Z[0][0] + sidx2;   // h2 -> buf0
  unsigned short* const w1_1 = &Z[1][0] + sidx1;   // h1 -> buf1
  unsigned short* const w2_1 = &Z[1][0] + sidx2;   // h2 -> buf1

  __syncthreads();

  // ---- prologue: h1(0) from x(0) only (h1(-1)=0, h2(-1)=0) ----
  {
    const float xv0 = xlds[n15 * 1095 + 0];
    const float xv1 = xlds[n15 * 1095 + 1];
    const float xv2 = xlds[n15 * 1095 + 2];
    const float p0 = fmaf(wiX[0], xv0, fmaf(wiY[0], xv1, fmaf(wiZ[0], xv2, b0v[0])));
    const float p2 = fmaf(wiX[2], xv0, fmaf(wiY[2], xv1, fmaf(wiZ[2], xv2, b0v[2])));
    const float p3 = fmaf(wiX[3], xv0, fmaf(wiY[3], xv1, fmaf(wiZ[3], xv2, b0v[3])));
    const float ig = sigm2(p0), gg = tanh2(p2), og = sigm2(p3);
    c1 = ig * gg;
    *w1_0 = h16(og * tanhc(c1));
  }
  __syncthreads();

  // ---- main loop: 182 step-pairs (t=0..363), then peel t=364 ----
  const float* xp = xlds + n15 * 1095 + 3;   // x(t+1), starting at t=0
  for (int it = 0; it < 182; ++it) {
    STEP(Z0p, w1_1, w2_1);   // even t: read buf0, write buf1
    STEP(Z1p, w1_0, w2_0);   // odd  t: read buf1, write buf0
  }

  // ---- peel t=364: L2 only, write output from registers ----
  {
    const halfx8 bh0 = Z0p[0],   bh1 = Z0p[64];
    const halfx8 bh2 = Z0p[128], bh3 = Z0p[192];
    floatx4 e0 = b1v;
    floatx4 e1 = {0.f, 0.f, 0.f, 0.f};
    e0 = MMH(a2h[0], bh0, e0);
    e1 = MMH(a2h[2], bh2, e1);
    e0 = MMH(a2h[1], bh1, e0);
    e1 = MMH(a2h[3], bh3, e1);
    const floatx4 e = e0 + e1;
    const float i2 = sigm2(e[0]), f2s = sigm2(e[1]);
    const float gg = tanh2(e[2]), o2 = sigm2(e[3]);
    c2 = fmaf(f2s, c2, i2 * gg);
    const float h2v = o2 * tanhc(c2);
    out[(size_t)(bbase + n15) * 64 + j] = h2v;
  }
}

extern "C" void kernel_launch(void* const* d_in, const int* in_sizes, int n_in,
                              void* d_out, int out_size, void* d_ws, size_t ws_size,
                              hipStream_t stream) {
  const float* x     = (const float*)d_in[0];
  const float* w_ih0 = (const float*)d_in[1];
  const float* w_hh0 = (const float*)d_in[2];
  const float* b_ih0 = (const float*)d_in[3];
  const float* b_hh0 = (const float*)d_in[4];
  const float* w_ih1 = (const float*)d_in[5];
  const float* w_hh1 = (const float*)d_in[6];
  const float* b_ih1 = (const float*)d_in[7];
  const float* b_hh1 = (const float*)d_in[8];
  float* out = (float*)d_out;

  const int B = in_sizes[0] / (TT * 3);   // 4096
  const int grid = B / NB;                // 256 blocks -> 1 per CU

  lstm2_mfma8<<<dim3(grid), dim3(NTH), 0, stream>>>(
      x, w_ih0, w_hh0, b_ih0, b_hh0, w_ih1, w_hh1, b_ih1, b_hh1, out);
}

// Round 11
// 344.219 us; speedup vs baseline: 1.0750x; 1.0750x over previous
//
#include <hip/hip_runtime.h>

#define TT 365
#define NB 16
#define NTH 1024   // 16 waves, 1 M-tile each -> 4 waves/SIMD
#define XLEN (NB * TT * 3)   // 17520 floats

typedef _Float16 halfx8 __attribute__((ext_vector_type(8)));
typedef float floatx4 __attribute__((ext_vector_type(4)));

#define MMH(A, B, C) __builtin_amdgcn_mfma_f32_16x16x32_f16((A), (B), (C), 0, 0, 0)

// Gate rows are PRE-SCALED: sigmoid rows by -log2e, g rows by -2log2e.
// So post-MFMA: yi,yf,yo = -log2e*x ; yg = -2log2e*x ; and
//   sigm(x) = 1/(1+2^yi) ; tanh(xg) = (1-2^yg)/(1+2^yg).
// Fused forms (saves 2 rcp/phase):
//   i*g        = (1-eg) / [(1+ei)(1+eg)]
//   o*tanh(c)  = (1-ec) / [(1+eo)(1+ec)]   with c kept in SG-scaled domain
#define SGP -2.8853900817779268f
#define SGN  2.8853900817779268f

__device__ __forceinline__ float rcpf(float x) { return __builtin_amdgcn_rcpf(x); }
__device__ __forceinline__ float ex2(float x)  { return __builtin_amdgcn_exp2f(x); }
__device__ __forceinline__ unsigned short h16(float v) {
  _Float16 h = (_Float16)v;
  return __builtin_bit_cast(unsigned short, h);
}

// weights -> plain fp16 (RNE); rel err 2^-12, verified harmless (R9 absmax flat)
#define LOADFRAG(SRC, SCALE, HI)                                               \
  do {                                                                         \
    _Pragma("unroll")                                                          \
    for (int jj = 0; jj < 8; ++jj) {                                           \
      (HI)[jj] = (_Float16)((SCALE) * (SRC)[jj]);                              \
    }                                                                          \
  } while (0)

// Fused gate tail: G = floatx4 pre-scaled pre-activations (i,f,g,o);
// CS = scaled cell state (lvalue), IDX = LDS write target for h.
#define GATE_TAIL(G, CS, ZW, IDX)                                              \
  do {                                                                         \
    const float ei = ex2((G)[0]);                                              \
    const float ef = ex2((G)[1]);                                              \
    const float eg = ex2((G)[2]);                                              \
    const float eo = ex2((G)[3]);                                              \
    const float fr = rcpf(1.0f + ef);                                          \
    const float R1 = rcpf((1.0f + ei) * (1.0f + eg));                          \
    (CS) = fminf(fmaf(fr, (CS), fmaf(SGN, eg, SGP) * R1), 126.0f);             \
    const float ec = ex2((CS));                                                \
    const float R2 = rcpf((1.0f + eo) * (1.0f + ec));                          \
    (ZW)[IDX] = h16((1.0f - ec) * R2);                                         \
  } while (0)

// L2 half-step: e = [w_ih1|w_hh1].[h1(t);h2(t-1)] + b1 ; combine2 -> h2(t)
#define E_PHASE(ZW)                                                            \
  do {                                                                         \
    floatx4 e = b1v;                                                           \
    e = MMH(a2h[0], bh0, e); e = MMH(a2h[1], bh1, e);                          \
    e = MMH(a2h[2], bh2, e); e = MMH(a2h[3], bh3, e);                          \
    GATE_TAIL(e, c2, ZW, sidx2);                                               \
  } while (0)

// L1 half-step: d = w_ih0.x(t+1) + b0 + w_hh0.h1(t) ; combine1 -> h1(t+1)
#define D_PHASE(ZW)                                                            \
  do {                                                                         \
    const floatx4 s0 = {xv0, xv0, xv0, xv0};                                   \
    const floatx4 s1 = {xv1, xv1, xv1, xv1};                                   \
    const floatx4 s2 = {xv2, xv2, xv2, xv2};                                   \
    floatx4 d = __builtin_elementwise_fma(wiX, s0,                             \
                  __builtin_elementwise_fma(wiY, s1,                           \
                    __builtin_elementwise_fma(wiZ, s2, b0v)));                 \
    d = MMH(a1h[0], bh0, d); d = MMH(a1h[1], bh1, d);                          \
    GATE_TAIL(d, c1, ZW, sidx1);                                               \
  } while (0)

#define STEP(ZR, ZW)                                                           \
  do {                                                                         \
    const halfx8* __restrict__ Z8 = (const halfx8*)(ZR);                       \
    const halfx8 bh0 = Z8[lane],       bh1 = Z8[64 + lane];                    \
    const halfx8 bh2 = Z8[128 + lane], bh3 = Z8[192 + lane];                   \
    const float xv0 = xp[0], xv1 = xp[1], xv2 = xp[2];                         \
    if (grpA) { E_PHASE(ZW); D_PHASE(ZW); }                                    \
    else      { D_PHASE(ZW); E_PHASE(ZW); }                                    \
    xp += 3;                                                                   \
    __syncthreads();                                                           \
  } while (0)

__global__ __launch_bounds__(NTH)
__attribute__((amdgpu_waves_per_eu(4, 4)))
void lstm2_mfma9(
    const float* __restrict__ x,
    const float* __restrict__ w_ih0, const float* __restrict__ w_hh0,
    const float* __restrict__ b_ih0, const float* __restrict__ b_hh0,
    const float* __restrict__ w_ih1, const float* __restrict__ w_hh1,
    const float* __restrict__ b_ih1, const float* __restrict__ b_hh1,
    float* __restrict__ out)
{
  __shared__ __align__(16) unsigned short Z[2][2048];  // fp16 h: [buf][kt][lane][8]
  __shared__ __align__(16) float xlds[XLEN];

  const int tid  = threadIdx.x;
  const int lane = tid & 63;
  const int wv   = tid >> 6;      // 0..15: one M-tile per wave
  const int n15  = lane & 15;
  const int quad = lane >> 4;
  const int bbase = blockIdx.x * NB;
  const bool grpA = ((wv >> 2) & 1) == 0;

  const float SS = -1.4426950408889634f;   // sigmoid rows
  const float SG = SGP;                    // g (tanh) rows
  const float sA = ((n15 & 3) == 2) ? SG : SS;

  halfx8 a1h[2];   // [kt]  L1 (K=64)
  halfx8 a2h[4];   // [kt]  L2 (K=128: [w_ih1|w_hh1])
  floatx4 wiX, wiY, wiZ, b0v, b1v;

  {
    const int mt   = wv;
    const int arow = (n15 & 3) * 64 + mt * 4 + (n15 >> 2);   // row-permuted A
    #pragma unroll
    for (int kt = 0; kt < 2; ++kt) {
      const float* src = w_hh0 + arow * 64 + kt * 32 + quad * 8;
      LOADFRAG(src, sA, a1h[kt]);
    }
    #pragma unroll
    for (int kt = 0; kt < 4; ++kt) {
      const int k0 = kt * 32 + quad * 8;
      const float* src = (k0 < 64) ? (w_ih1 + arow * 64 + k0)
                                   : (w_hh1 + arow * 64 + (k0 - 64));
      LOADFRAG(src, sA, a2h[kt]);
    }
    #pragma unroll
    for (int r = 0; r < 4; ++r) {
      const int crow = r * 64 + mt * 4 + quad;
      const float sC = (r == 2) ? SG : SS;
      wiX[r] = sC * w_ih0[crow * 3 + 0];
      wiY[r] = sC * w_ih0[crow * 3 + 1];
      wiZ[r] = sC * w_ih0[crow * 3 + 2];
      b0v[r] = sC * (b_ih0[crow] + b_hh0[crow]);
      b1v[r] = sC * (b_ih1[crow] + b_hh1[crow]);
    }
  }

  const int j = wv * 4 + quad;    // this thread's hidden unit (0..63)
  const int sidx1 = (j >> 5) * 512 + ((j >> 3) & 3) * 128 + n15 * 8 + (j & 7);
  const int sidx2 = sidx1 + 1024;

  {
    const float* xg = x + (size_t)bbase * (TT * 3);
    for (int i = tid; i < XLEN; i += NTH) xlds[i] = xg[i];
    for (int i = tid; i < 2048; i += NTH) { Z[0][i] = 0; Z[1][i] = 0; }
  }

  // scaled-domain cell states: c*_s = SG * c_true  (so ec = exp2(c_s) directly)
  float c1 = 0.f, c2 = 0.f;
  unsigned short* const Zb0 = &Z[0][0];
  unsigned short* const Zb1 = &Z[1][0];

  __syncthreads();

  // ---- prologue: h1(0) from x(0) only (h1(-1)=0, h2(-1)=0) ----
  {
    const float xv0 = xlds[n15 * 1095 + 0];
    const float xv1 = xlds[n15 * 1095 + 1];
    const float xv2 = xlds[n15 * 1095 + 2];
    const float p0 = fmaf(wiX[0], xv0, fmaf(wiY[0], xv1, fmaf(wiZ[0], xv2, b0v[0])));
    const float p2 = fmaf(wiX[2], xv0, fmaf(wiY[2], xv1, fmaf(wiZ[2], xv2, b0v[2])));
    const float p3 = fmaf(wiX[3], xv0, fmaf(wiY[3], xv1, fmaf(wiZ[3], xv2, b0v[3])));
    const float ei = ex2(p0), eg = ex2(p2), eo = ex2(p3);
    const float R1 = rcpf((1.0f + ei) * (1.0f + eg));
    c1 = fmaf(SGN, eg, SGP) * R1;          // f-term is zero (c=0)
    const float ec = ex2(c1);
    const float R2 = rcpf((1.0f + eo) * (1.0f + ec));
    Zb0[sidx1] = h16((1.0f - ec) * R2);
  }
  __syncthreads();

  // ---- main loop: 182 step-pairs (t=0..363), then peel t=364 ----
  const float* xp = xlds + n15 * 1095 + 3;   // x(t+1), starting at t=0
  for (int it = 0; it < 182; ++it) {
    STEP(Zb0, Zb1);
    STEP(Zb1, Zb0);
  }

  // ---- peel t=364: L2 only, write output from registers ----
  {
    const halfx8* __restrict__ Z8 = (const halfx8*)Zb0;
    const halfx8 bh0 = Z8[lane],       bh1 = Z8[64 + lane];
    const halfx8 bh2 = Z8[128 + lane], bh3 = Z8[192 + lane];
    floatx4 e = b1v;
    e = MMH(a2h[0], bh0, e); e = MMH(a2h[1], bh1, e);
    e = MMH(a2h[2], bh2, e); e = MMH(a2h[3], bh3, e);
    const float ei = ex2(e[0]), ef = ex2(e[1]), eg = ex2(e[2]), eo = ex2(e[3]);
    const float fr = rcpf(1.0f + ef);
    const float R1 = rcpf((1.0f + ei) * (1.0f + eg));
    c2 = fminf(fmaf(fr, c2, fmaf(SGN, eg, SGP) * R1), 126.0f);
    const float ec = ex2(c2);
    const float R2 = rcpf((1.0f + eo) * (1.0f + ec));
    const float h2v = (1.0f - ec) * R2;
    out[(size_t)(bbase + n15) * 64 + j] = h2v;
  }
}

extern "C" void kernel_launch(void* const* d_in, const int* in_sizes, int n_in,
                              void* d_out, int out_size, void* d_ws, size_t ws_size,
                              hipStream_t stream) {
  const float* x     = (const float*)d_in[0];
  const float* w_ih0 = (const float*)d_in[1];
  const float* w_hh0 = (const float*)d_in[2];
  const float* b_ih0 = (const float*)d_in[3];
  const float* b_hh0 = (const float*)d_in[4];
  const float* w_ih1 = (const float*)d_in[5];
  const float* w_hh1 = (const float*)d_in[6];
  const float* b_ih1 = (const float*)d_in[7];
  const float* b_hh1 = (const float*)d_in[8];
  float* out = (float*)d_out;

  const int B = in_sizes[0] / (TT * 3);   // 4096
  const int grid = B / NB;                // 256 blocks -> 1 per CU

  lstm2_mfma9<<<dim3(grid), dim3(NTH), 0, stream>>>(
      x, w_ih0, w_hh0, b_ih0, b_hh0, w_ih1, w_hh1, b_ih1, b_hh1, out);
}

// Round 12
// 311.915 us; speedup vs baseline: 1.1864x; 1.1036x over previous
//
#include <hip/hip_runtime.h>

#define TT 365
#define NB 16
#define NTH 1024   // 16 waves: 0-7 = L2 role, 8-15 = L1 role (2E+2D per SIMD)
#define XLEN (NB * TT * 3)

typedef _Float16 halfx8 __attribute__((ext_vector_type(8)));
typedef float floatx4 __attribute__((ext_vector_type(4)));
typedef float floatx2 __attribute__((ext_vector_type(2)));

#define MMH(A, B, C) __builtin_amdgcn_mfma_f32_16x16x32_f16((A), (B), (C), 0, 0, 0)

// Gate rows PRE-SCALED: sigmoid rows by -log2e, g rows by -2log2e (R11 scheme).
#define SGP -2.8853900817779268f
#define SGN  2.8853900817779268f
#define SS_  -1.4426950408889634f

static __device__ __forceinline__ float rcpf(float x) { return __builtin_amdgcn_rcpf(x); }
static __device__ __forceinline__ float ex2(float x)  { return __builtin_amdgcn_exp2f(x); }
static __device__ __forceinline__ unsigned short h16(float v) {
  _Float16 h = (_Float16)v;
  return __builtin_bit_cast(unsigned short, h);
}

#define LOADFRAG(SRC, SCALE, HI)                                               \
  do {                                                                         \
    _Pragma("unroll")                                                          \
    for (int jj = 0; jj < 8; ++jj) {                                           \
      (HI)[jj] = (_Float16)((SCALE) * (SRC)[jj]);                              \
    }                                                                          \
  } while (0)

// Packed gate tail over TWO independent gate-sets (PA, PB = floatx4 pre-acts
// of tiles 0/1). CS2 = float2 scaled cell state. Produces float2 h in HOUT.
// Identical arithmetic to R11's GATE_TAIL, executed pairwise (v_pk_*_f32).
#define PTAIL_CORE(PA, PB, CS2, HOUT)                                          \
  const floatx2 one_ = {1.0f, 1.0f};                                           \
  const floatx2 ei_ = {ex2((PA)[0]), ex2((PB)[0])};                            \
  const floatx2 ef_ = {ex2((PA)[1]), ex2((PB)[1])};                            \
  const floatx2 eg_ = {ex2((PA)[2]), ex2((PB)[2])};                            \
  const floatx2 eo_ = {ex2((PA)[3]), ex2((PB)[3])};                            \
  const floatx2 fd_ = one_ + ef_;                                              \
  const floatx2 fr_ = {rcpf(fd_.x), rcpf(fd_.y)};                              \
  const floatx2 P1_ = (one_ + ei_) * (one_ + eg_);                             \
  const floatx2 R1_ = {rcpf(P1_.x), rcpf(P1_.y)};                              \
  const floatx2 sgn2_ = {SGN, SGN};                                            \
  const floatx2 sgp2_ = {SGP, SGP};                                            \
  (CS2) = fr_ * (CS2) + (sgn2_ * eg_ + sgp2_) * R1_;                           \
  (CS2).x = fminf((CS2).x, 126.0f);                                            \
  (CS2).y = fminf((CS2).y, 126.0f);                                            \
  const floatx2 ec_ = {ex2((CS2).x), ex2((CS2).y)};                            \
  const floatx2 P2_ = (one_ + eo_) * (one_ + ec_);                             \
  const floatx2 R2_ = {rcpf(P2_.x), rcpf(P2_.y)};                              \
  const floatx2 HOUT = (one_ - ec_) * R2_;

#define PTAIL(PA, PB, CS2, ZW, IA, IB)                                         \
  do {                                                                         \
    PTAIL_CORE(PA, PB, CS2, hv_)                                               \
    (ZW)[IA] = h16(hv_.x);                                                     \
    (ZW)[IB] = h16(hv_.y);                                                     \
  } while (0)

__global__ __launch_bounds__(NTH)
__attribute__((amdgpu_waves_per_eu(4, 4)))
void lstm2_mfma10(
    const float* __restrict__ x,
    const float* __restrict__ w_ih0, const float* __restrict__ w_hh0,
    const float* __restrict__ b_ih0, const float* __restrict__ b_hh0,
    const float* __restrict__ w_ih1, const float* __restrict__ w_hh1,
    const float* __restrict__ b_ih1, const float* __restrict__ b_hh1,
    float* __restrict__ out)
{
  __shared__ __align__(16) unsigned short Z[2][2048];  // fp16 h: [buf][kt][lane][8]
  __shared__ __align__(16) float xlds[XLEN];

  const int tid  = threadIdx.x;
  const int lane = tid & 63;
  const int wv   = tid >> 6;
  const int n15  = lane & 15;
  const int quad = lane >> 4;
  const int bbase = blockIdx.x * NB;
  const float sA = ((n15 & 3) == 2) ? SGP : SS_;

  // shared staging: x -> LDS, zero both Z buffers
  {
    const float* xg = x + (size_t)bbase * (TT * 3);
    for (int i = tid; i < XLEN; i += NTH) xlds[i] = xg[i];
    for (int i = tid; i < 2048; i += NTH) { Z[0][i] = 0; Z[1][i] = 0; }
  }
  unsigned short* const Zb0 = &Z[0][0];
  unsigned short* const Zb1 = &Z[1][0];
  __syncthreads();   // barrier #1 (both roles)

  if (wv < 8) {
    // ================= E role: layer-2 GEMM + combine2 =================
    const int w = wv;
    halfx8 a2[2][4];
    floatx4 b1v[2];
    #pragma unroll
    for (int tt = 0; tt < 2; ++tt) {
      const int mt   = 2 * w + tt;
      const int arow = (n15 & 3) * 64 + mt * 4 + (n15 >> 2);
      #pragma unroll
      for (int kt = 0; kt < 4; ++kt) {
        const int k0 = kt * 32 + quad * 8;
        const float* src = (k0 < 64) ? (w_ih1 + arow * 64 + k0)
                                     : (w_hh1 + arow * 64 + (k0 - 64));
        LOADFRAG(src, sA, a2[tt][kt]);
      }
      #pragma unroll
      for (int r = 0; r < 4; ++r) {
        const int crow = r * 64 + mt * 4 + quad;
        const float sC = (r == 2) ? SGP : SS_;
        b1v[tt][r] = sC * (b_ih1[crow] + b_hh1[crow]);
      }
    }
    const int j0 = 8 * w + quad, j1 = 8 * w + 4 + quad;
    const int si0 = 1024 + (j0 >> 5) * 512 + ((j0 >> 3) & 3) * 128 + n15 * 8 + (j0 & 7);
    const int si1 = 1024 + (j1 >> 5) * 512 + ((j1 >> 3) & 3) * 128 + n15 * 8 + (j1 & 7);
    floatx2 c2v = {0.f, 0.f};
    const halfx8* const Z0r = (const halfx8*)Zb0 + lane;
    const halfx8* const Z1r = (const halfx8*)Zb1 + lane;

    __syncthreads();   // barrier #2 (matches D prologue barrier)

#define ESTEP(ZRP, ZW)                                                         \
    do {                                                                       \
      const halfx8 bh0 = (ZRP)[0],   bh1 = (ZRP)[64];                          \
      const halfx8 bh2 = (ZRP)[128], bh3 = (ZRP)[192];                         \
      floatx4 e0 = b1v[0], e1 = b1v[1];                                        \
      e0 = MMH(a2[0][0], bh0, e0); e0 = MMH(a2[0][1], bh1, e0);                \
      e0 = MMH(a2[0][2], bh2, e0); e0 = MMH(a2[0][3], bh3, e0);                \
      e1 = MMH(a2[1][0], bh0, e1); e1 = MMH(a2[1][1], bh1, e1);                \
      e1 = MMH(a2[1][2], bh2, e1); e1 = MMH(a2[1][3], bh3, e1);                \
      PTAIL(e0, e1, c2v, ZW, si0, si1);                                        \
      __syncthreads();                                                         \
    } while (0)

    for (int it = 0; it < 182; ++it) {
      ESTEP(Z0r, Zb1);
      ESTEP(Z1r, Zb0);
    }

    // peel t=364: gates2 -> h2(364) -> out
    {
      const halfx8 bh0 = Z0r[0],   bh1 = Z0r[64];
      const halfx8 bh2 = Z0r[128], bh3 = Z0r[192];
      floatx4 e0 = b1v[0], e1 = b1v[1];
      e0 = MMH(a2[0][0], bh0, e0); e0 = MMH(a2[0][1], bh1, e0);
      e0 = MMH(a2[0][2], bh2, e0); e0 = MMH(a2[0][3], bh3, e0);
      e1 = MMH(a2[1][0], bh0, e1); e1 = MMH(a2[1][1], bh1, e1);
      e1 = MMH(a2[1][2], bh2, e1); e1 = MMH(a2[1][3], bh3, e1);
      PTAIL_CORE(e0, e1, c2v, hv_)
      out[(size_t)(bbase + n15) * 64 + j0] = hv_.x;
      out[(size_t)(bbase + n15) * 64 + j1] = hv_.y;
    }
  } else {
    // ================= D role: layer-1 GEMM + combine1 =================
    const int u = wv - 8;
    halfx8 a1[2][2];
    floatx4 wiX[2], wiY[2], wiZ[2], b0v[2];
    #pragma unroll
    for (int tt = 0; tt < 2; ++tt) {
      const int mt   = 2 * u + tt;
      const int arow = (n15 & 3) * 64 + mt * 4 + (n15 >> 2);
      #pragma unroll
      for (int kt = 0; kt < 2; ++kt) {
        const float* src = w_hh0 + arow * 64 + kt * 32 + quad * 8;
        LOADFRAG(src, sA, a1[tt][kt]);
      }
      #pragma unroll
      for (int r = 0; r < 4; ++r) {
        const int crow = r * 64 + mt * 4 + quad;
        const float sC = (r == 2) ? SGP : SS_;
        wiX[tt][r] = sC * w_ih0[crow * 3 + 0];
        wiY[tt][r] = sC * w_ih0[crow * 3 + 1];
        wiZ[tt][r] = sC * w_ih0[crow * 3 + 2];
        b0v[tt][r] = sC * (b_ih0[crow] + b_hh0[crow]);
      }
    }
    const int j0 = 8 * u + quad, j1 = 8 * u + 4 + quad;
    const int si0 = (j0 >> 5) * 512 + ((j0 >> 3) & 3) * 128 + n15 * 8 + (j0 & 7);
    const int si1 = (j1 >> 5) * 512 + ((j1 >> 3) & 3) * 128 + n15 * 8 + (j1 & 7);
    floatx2 c1v = {0.f, 0.f};
    const halfx8* const Z0r = (const halfx8*)Zb0 + lane;
    const halfx8* const Z1r = (const halfx8*)Zb1 + lane;

    // prologue: h1(0) from x(0) only (h1(-1)=0) -> Zb0
    {
      const float xv0 = xlds[n15 * 1095 + 0];
      const float xv1 = xlds[n15 * 1095 + 1];
      const float xv2 = xlds[n15 * 1095 + 2];
      const floatx4 s0 = {xv0, xv0, xv0, xv0};
      const floatx4 s1 = {xv1, xv1, xv1, xv1};
      const floatx4 s2 = {xv2, xv2, xv2, xv2};
      floatx4 d0 = __builtin_elementwise_fma(wiX[0], s0,
                     __builtin_elementwise_fma(wiY[0], s1,
                       __builtin_elementwise_fma(wiZ[0], s2, b0v[0])));
      floatx4 d1 = __builtin_elementwise_fma(wiX[1], s0,
                     __builtin_elementwise_fma(wiY[1], s1,
                       __builtin_elementwise_fma(wiZ[1], s2, b0v[1])));
      PTAIL(d0, d1, c1v, Zb0, si0, si1);   // c1v=0 -> f-term vanishes
    }
    __syncthreads();   // barrier #2

    const float* xp = xlds + n15 * 1095 + 3;   // x(t+1), starting at t=0

#define DSTEP(ZRP, ZW)                                                         \
    do {                                                                       \
      const halfx8 bh0 = (ZRP)[0], bh1 = (ZRP)[64];                            \
      const float xv0 = xp[0], xv1 = xp[1], xv2 = xp[2];                       \
      const floatx4 s0 = {xv0, xv0, xv0, xv0};                                 \
      const floatx4 s1 = {xv1, xv1, xv1, xv1};                                 \
      const floatx4 s2 = {xv2, xv2, xv2, xv2};                                 \
      floatx4 d0 = __builtin_elementwise_fma(wiX[0], s0,                       \
                     __builtin_elementwise_fma(wiY[0], s1,                     \
                       __builtin_elementwise_fma(wiZ[0], s2, b0v[0])));        \
      floatx4 d1 = __builtin_elementwise_fma(wiX[1], s0,                       \
                     __builtin_elementwise_fma(wiY[1], s1,                     \
                       __builtin_elementwise_fma(wiZ[1], s2, b0v[1])));        \
      d0 = MMH(a1[0][0], bh0, d0); d0 = MMH(a1[0][1], bh1, d0);                \
      d1 = MMH(a1[1][0], bh0, d1); d1 = MMH(a1[1][1], bh1, d1);                \
      PTAIL(d0, d1, c1v, ZW, si0, si1);                                        \
      xp += 3;                                                                 \
      __syncthreads();                                                         \
    } while (0)

    for (int it = 0; it < 182; ++it) {
      DSTEP(Z0r, Zb1);
      DSTEP(Z1r, Zb0);
    }
    // peel t=364: nothing for D (no barrier; E peel has none either)
  }
}

extern "C" void kernel_launch(void* const* d_in, const int* in_sizes, int n_in,
                              void* d_out, int out_size, void* d_ws, size_t ws_size,
                              hipStream_t stream) {
  const float* x     = (const float*)d_in[0];
  const float* w_ih0 = (const float*)d_in[1];
  const float* w_hh0 = (const float*)d_in[2];
  const float* b_ih0 = (const float*)d_in[3];
  const float* b_hh0 = (const float*)d_in[4];
  const float* w_ih1 = (const float*)d_in[5];
  const float* w_hh1 = (const float*)d_in[6];
  const float* b_ih1 = (const float*)d_in[7];
  const float* b_hh1 = (const float*)d_in[8];
  float* out = (float*)d_out;

  const int B = in_sizes[0] / (TT * 3);   // 4096
  const int grid = B / NB;                // 256 blocks -> 1 per CU

  lstm2_mfma10<<<dim3(grid), dim3(NTH), 0, stream>>>(
      x, w_ih0, w_hh0, b_ih0, b_hh0, w_ih1, w_hh1, b_ih1, b_hh1, out);
}

// Round 14
// 304.781 us; speedup vs baseline: 1.2142x; 1.0234x over previous
//
#include <hip/hip_runtime.h>

#define TT 365
#define NB 16
#define NTH 1024   // 16 waves: 0-7 = L2 (E) role, 8-15 = L1 (D) role
#define XLEN (NB * TT * 3)

typedef _Float16 halfx8 __attribute__((ext_vector_type(8)));
typedef float floatx4 __attribute__((ext_vector_type(4)));
typedef float floatx2 __attribute__((ext_vector_type(2)));

#define MMH(A, B, C) __builtin_amdgcn_mfma_f32_16x16x32_f16((A), (B), (C), 0, 0, 0)

// Gate rows PRE-SCALED: sigmoid rows by -log2e, g rows by -2log2e.
#define SGP -2.8853900817779268f
#define SGN  2.8853900817779268f
#define SS_  -1.4426950408889634f

static __device__ __forceinline__ float rcpf(float x) { return __builtin_amdgcn_rcpf(x); }
static __device__ __forceinline__ float ex2(float x)  { return __builtin_amdgcn_exp2f(x); }

#define LOADFRAG(SRC, SCALE, HI)                                               \
  do {                                                                         \
    _Pragma("unroll")                                                          \
    for (int jj = 0; jj < 8; ++jj) {                                           \
      (HI)[jj] = (_Float16)((SCALE) * (SRC)[jj]);                              \
    }                                                                          \
  } while (0)

// Packed tail, combined-rcp cell update (1 rcp for f & i*g paths):
//   c' = [c*(1+ei)(1+eg) + SGP*(1-eg)*(1+ef)] / [(1+ef)(1+ei)(1+eg)]
//   h  = (1-ec) / [(1+eo)(1+ec)],  ec = 2^c'  (c kept in SG-scaled domain)
#define PTAIL_CORE(PA, PB, CS2, HOUT)                                          \
  const floatx2 one_ = {1.0f, 1.0f};                                           \
  const floatx2 ei_ = {ex2((PA)[0]), ex2((PB)[0])};                            \
  const floatx2 ef_ = {ex2((PA)[1]), ex2((PB)[1])};                            \
  const floatx2 eg_ = {ex2((PA)[2]), ex2((PB)[2])};                            \
  const floatx2 eo_ = {ex2((PA)[3]), ex2((PB)[3])};                            \
  const floatx2 sgn2_ = {SGN, SGN};                                            \
  const floatx2 sgp2_ = {SGP, SGP};                                            \
  const floatx2 fd_ = one_ + ef_;                                              \
  const floatx2 P1_ = (one_ + ei_) * (one_ + eg_);                             \
  const floatx2 Dp_ = P1_ * fd_;                                               \
  const floatx2 R_  = {rcpf(Dp_.x), rcpf(Dp_.y)};                              \
  const floatx2 T_  = (sgn2_ * eg_ + sgp2_) * fd_;                             \
  (CS2) = ((CS2) * P1_ + T_) * R_;                                             \
  (CS2).x = fminf((CS2).x, 60.0f);                                             \
  (CS2).y = fminf((CS2).y, 60.0f);                                             \
  const floatx2 ec_ = {ex2((CS2).x), ex2((CS2).y)};                            \
  const floatx2 P2_ = (one_ + eo_) * (one_ + ec_);                             \
  const floatx2 R2_ = {rcpf(P2_.x), rcpf(P2_.y)};                              \
  const floatx2 HOUT = (one_ - ec_) * R2_;

// pack both h (adjacent units) into one b32 LDS write
#define PTAIL(PA, PB, CS2, ZW32, WIDX)                                         \
  do {                                                                         \
    PTAIL_CORE(PA, PB, CS2, hv_)                                               \
    (ZW32)[WIDX] =                                                             \
        __builtin_bit_cast(unsigned, __builtin_amdgcn_cvt_pkrtz(hv_.x, hv_.y)); \
  } while (0)

__global__ __launch_bounds__(NTH)
__attribute__((amdgpu_waves_per_eu(4, 4)))
void lstm2_mfma11(
    const float* __restrict__ x,
    const float* __restrict__ w_ih0, const float* __restrict__ w_hh0,
    const float* __restrict__ b_ih0, const float* __restrict__ b_hh0,
    const float* __restrict__ w_ih1, const float* __restrict__ w_hh1,
    const float* __restrict__ b_ih1, const float* __restrict__ b_hh1,
    float* __restrict__ out)
{
  __shared__ __align__(16) unsigned short Z[2][2048];  // fp16 h: [buf][kt][lane][8]
  __shared__ __align__(16) float xh[TT * 16 * 4];      // x re-laid: [t][b][4] (pad unused)

  const int tid  = threadIdx.x;
  const int lane = tid & 63;
  const int wv   = tid >> 6;
  const int n15  = lane & 15;
  const int quad = lane >> 4;
  const int bbase = blockIdx.x * NB;
  const float sA = ((n15 & 3) == 2) ? SGP : SS_;

  // stage x -> [t][b][4] layout (coalesced global reads, scattered LDS writes)
  {
    const float* xg = x + (size_t)bbase * (TT * 3);
    for (int i = tid; i < XLEN; i += NTH) {
      const int b = i / 1095;
      const int rem = i - b * 1095;
      const int t = rem / 3;
      const int c = rem - 3 * t;
      xh[(t * 16 + b) * 4 + c] = xg[i];
    }
    for (int i = tid; i < 2048; i += NTH) { Z[0][i] = 0; Z[1][i] = 0; }
  }
  unsigned short* const Zb0 = &Z[0][0];
  unsigned short* const Zb1 = &Z[1][0];
  __syncthreads();   // barrier #1

  // Adjacent-unit retiling: wave w, tile A -> units 8w+2q (q=quad), tile B -> +1.
  // Thread's two h values are units j0=8w+2q, j1=j0+1 -> one packed b32 write.

  if (wv < 8) {
    // ================= E role: layer-2 GEMM + combine2 =================
    const int w = wv;
    halfx8 a2[2][4];
    floatx4 b1v[2];
    #pragma unroll
    for (int tt = 0; tt < 2; ++tt) {
      const int arow = (n15 & 3) * 64 + 8 * w + 2 * (n15 >> 2) + tt;
      #pragma unroll
      for (int kt = 0; kt < 4; ++kt) {
        const int k0 = kt * 32 + quad * 8;
        const float* src = (k0 < 64) ? (w_ih1 + arow * 64 + k0)
                                     : (w_hh1 + arow * 64 + (k0 - 64));
        LOADFRAG(src, sA, a2[tt][kt]);
      }
      #pragma unroll
      for (int r = 0; r < 4; ++r) {
        const int crow = r * 64 + 8 * w + 2 * quad + tt;
        const float sC = (r == 2) ? SGP : SS_;
        b1v[tt][r] = sC * (b_ih1[crow] + b_hh1[crow]);
      }
    }
    const int j0 = 8 * w + 2 * quad;
    const int widx = 512 + (w >> 2) * 256 + (w & 3) * 64 + n15 * 4 + quad;
    floatx2 c2v = {0.f, 0.f};
    const halfx8* const Z0r = (const halfx8*)Zb0 + lane;
    const halfx8* const Z1r = (const halfx8*)Zb1 + lane;

    __syncthreads();   // barrier #2 (matches D prologue barrier)

#define ESTEP(ZRP, ZW32)                                                       \
    do {                                                                       \
      const halfx8 bh0 = (ZRP)[0],   bh1 = (ZRP)[64];                          \
      const halfx8 bh2 = (ZRP)[128], bh3 = (ZRP)[192];                         \
      floatx4 e0 = b1v[0], e1 = b1v[1];                                        \
      e0 = MMH(a2[0][0], bh0, e0); e0 = MMH(a2[0][1], bh1, e0);                \
      e0 = MMH(a2[0][2], bh2, e0); e0 = MMH(a2[0][3], bh3, e0);                \
      e1 = MMH(a2[1][0], bh0, e1); e1 = MMH(a2[1][1], bh1, e1);                \
      e1 = MMH(a2[1][2], bh2, e1); e1 = MMH(a2[1][3], bh3, e1);                \
      PTAIL(e0, e1, c2v, ZW32, widx);                                          \
      __syncthreads();                                                         \
    } while (0)

    for (int it = 0; it < 182; ++it) {
      ESTEP(Z0r, (unsigned*)Zb1);
      ESTEP(Z1r, (unsigned*)Zb0);
    }

    // peel t=364: gates2 -> h2(364) -> out (units j0, j0+1 adjacent)
    {
      const halfx8 bh0 = Z0r[0],   bh1 = Z0r[64];
      const halfx8 bh2 = Z0r[128], bh3 = Z0r[192];
      floatx4 e0 = b1v[0], e1 = b1v[1];
      e0 = MMH(a2[0][0], bh0, e0); e0 = MMH(a2[0][1], bh1, e0);
      e0 = MMH(a2[0][2], bh2, e0); e0 = MMH(a2[0][3], bh3, e0);
      e1 = MMH(a2[1][0], bh0, e1); e1 = MMH(a2[1][1], bh1, e1);
      e1 = MMH(a2[1][2], bh2, e1); e1 = MMH(a2[1][3], bh3, e1);
      PTAIL_CORE(e0, e1, c2v, hv_)
      *(floatx2*)(out + (size_t)(bbase + n15) * 64 + j0) = hv_;
    }
  } else {
    // ================= D role: layer-1 GEMM + combine1 =================
    const int u = wv - 8;
    halfx8 a1[2][2];
    floatx4 wiX[2], wiY[2], wiZ[2], b0v[2];
    #pragma unroll
    for (int tt = 0; tt < 2; ++tt) {
      const int arow = (n15 & 3) * 64 + 8 * u + 2 * (n15 >> 2) + tt;
      #pragma unroll
      for (int kt = 0; kt < 2; ++kt) {
        const float* src = w_hh0 + arow * 64 + kt * 32 + quad * 8;
        LOADFRAG(src, sA, a1[tt][kt]);
      }
      #pragma unroll
      for (int r = 0; r < 4; ++r) {
        const int crow = r * 64 + 8 * u + 2 * quad + tt;
        const float sC = (r == 2) ? SGP : SS_;
        wiX[tt][r] = sC * w_ih0[crow * 3 + 0];
        wiY[tt][r] = sC * w_ih0[crow * 3 + 1];
        wiZ[tt][r] = sC * w_ih0[crow * 3 + 2];
        b0v[tt][r] = sC * (b_ih0[crow] + b_hh0[crow]);
      }
    }
    const int widx = (u >> 2) * 256 + (u & 3) * 64 + n15 * 4 + quad;  // h1 region
    floatx2 c1v = {0.f, 0.f};
    const halfx8* const Z0r = (const halfx8*)Zb0 + lane;
    const halfx8* const Z1r = (const halfx8*)Zb1 + lane;

    // prologue: h1(0) from x(0) only -> Zb0
    {
      const floatx4 xv = *(const floatx4*)(xh + n15 * 4);
      const floatx4 s0 = {xv[0], xv[0], xv[0], xv[0]};
      const floatx4 s1 = {xv[1], xv[1], xv[1], xv[1]};
      const floatx4 s2 = {xv[2], xv[2], xv[2], xv[2]};
      floatx4 d0 = __builtin_elementwise_fma(wiX[0], s0,
                     __builtin_elementwise_fma(wiY[0], s1,
                       __builtin_elementwise_fma(wiZ[0], s2, b0v[0])));
      floatx4 d1 = __builtin_elementwise_fma(wiX[1], s0,
                     __builtin_elementwise_fma(wiY[1], s1,
                       __builtin_elementwise_fma(wiZ[1], s2, b0v[1])));
      PTAIL(d0, d1, c1v, (unsigned*)Zb0, widx);   // c1v=0 -> f-term vanishes
    }
    __syncthreads();   // barrier #2

    const float* xp = xh + 64 + n15 * 4;   // x(t+1), one b128 per step

#define DSTEP(ZRP, ZW32)                                                       \
    do {                                                                       \
      const halfx8 bh0 = (ZRP)[0], bh1 = (ZRP)[64];                            \
      const floatx4 xv = *(const floatx4*)xp;                                  \
      const floatx4 s0 = {xv[0], xv[0], xv[0], xv[0]};                         \
      const floatx4 s1 = {xv[1], xv[1], xv[1], xv[1]};                         \
      const floatx4 s2 = {xv[2], xv[2], xv[2], xv[2]};                         \
      floatx4 d0 = __builtin_elementwise_fma(wiX[0], s0,                       \
                     __builtin_elementwise_fma(wiY[0], s1,                     \
                       __builtin_elementwise_fma(wiZ[0], s2, b0v[0])));        \
      floatx4 d1 = __builtin_elementwise_fma(wiX[1], s0,                       \
                     __builtin_elementwise_fma(wiY[1], s1,                     \
                       __builtin_elementwise_fma(wiZ[1], s2, b0v[1])));        \
      d0 = MMH(a1[0][0], bh0, d0); d0 = MMH(a1[0][1], bh1, d0);                \
      d1 = MMH(a1[1][0], bh0, d1); d1 = MMH(a1[1][1], bh1, d1);                \
      PTAIL(d0, d1, c1v, ZW32, widx);                                          \
      xp += 64;                                                                \
      __syncthreads();                                                         \
    } while (0)

    for (int it = 0; it < 182; ++it) {
      DSTEP(Z0r, (unsigned*)Zb1);
      DSTEP(Z1r, (unsigned*)Zb0);
    }
    // peel t=364: nothing for D
  }
}

extern "C" void kernel_launch(void* const* d_in, const int* in_sizes, int n_in,
                              void* d_out, int out_size, void* d_ws, size_t ws_size,
                              hipStream_t stream) {
  const float* x     = (const float*)d_in[0];
  const float* w_ih0 = (const float*)d_in[1];
  const float* w_hh0 = (const float*)d_in[2];
  const float* b_ih0 = (const float*)d_in[3];
  const float* b_hh0 = (const float*)d_in[4];
  const float* w_ih1 = (const float*)d_in[5];
  const float* w_hh1 = (const float*)d_in[6];
  const float* b_ih1 = (const float*)d_in[7];
  const float* b_hh1 = (const float*)d_in[8];
  float* out = (float*)d_out;

  const int B = in_sizes[0] / (TT * 3);   // 4096
  const int grid = B / NB;                // 256 blocks -> 1 per CU

  lstm2_mfma11<<<dim3(grid), dim3(NTH), 0, stream>>>(
      x, w_ih0, w_hh0, b_ih0, b_hh0, w_ih1, w_hh1, b_ih1, b_hh1, out);
}